// Round 4
// baseline (285.454 us; speedup 1.0000x reference)
//
#include <hip/hip_runtime.h>
#include <hip/hip_bf16.h>
#include <math.h>

#define N_NODES 10000
#define N_EDGES 160000

typedef __attribute__((ext_vector_type(8))) short bf16x8;
typedef __attribute__((ext_vector_type(4))) float f32x4;

static __device__ inline unsigned short f2b(float v) {
    __hip_bfloat16 b = __float2bfloat16(v);
    return *reinterpret_cast<unsigned short*>(&b);
}

// ---------- zero cnt_src/cnt_dst + transpose all three w2 ----------
// w2t[i*1024 + o*32 + k] = w2[k*(din*32) + i*32 + o]
__global__ __launch_bounds__(256) void k_tw2z(const float* __restrict__ s0,
                                              const float* __restrict__ s1,
                                              const float* __restrict__ s2,
                                              float* __restrict__ t0,
                                              float* __restrict__ t1,
                                              float* __restrict__ t2,
                                              int* __restrict__ cnt2) {  // cnt_src|cnt_dst, 20480 ints
    int tid = blockIdx.x * 256 + threadIdx.x;
    if (tid < 20480) { cnt2[tid] = 0; return; }
    int d = tid - 20480;
    if (d < 4096) {                            // layer 0, din=4
        int i = d >> 10, j = d & 1023, o = j >> 5, k = j & 31;
        t0[d] = s0[k * 128 + i * 32 + o];
    } else if (d < 4096 + 32768) {
        int q = d - 4096;
        int i = q >> 10, j = q & 1023, o = j >> 5, k = j & 31;
        t1[q] = s1[k * 1024 + i * 32 + o];
    } else if (d < 4096 + 65536) {
        int q = d - 4096 - 32768;
        int i = q >> 10, j = q & 1023, o = j >> 5, k = j & 31;
        t2[q] = s2[k * 1024 + i * 32 + o];
    }
}

// ---------- histograms for both src and dst ----------
__global__ __launch_bounds__(256) void k_hist(const int* __restrict__ ei,
                                              int* __restrict__ cnt_src,
                                              int* __restrict__ cnt_dst) {
    int e = blockIdx.x * 256 + threadIdx.x;
    if (e >= N_EDGES) return;
    atomicAdd(&cnt_src[ei[e]], 1);
    atomicAdd(&cnt_dst[ei[N_EDGES + e]], 1);
}

// grid=2: block 0 scans src counts, block 1 scans dst counts
__global__ __launch_bounds__(256) void k_scan(const int* __restrict__ cnt_src,
                                              const int* __restrict__ cnt_dst,
                                              int* __restrict__ off_src,
                                              int* __restrict__ off_dst,
                                              int* __restrict__ cur_src,
                                              int* __restrict__ cur_dst) {
    const int* cnt = blockIdx.x == 0 ? cnt_src : cnt_dst;
    int* off = blockIdx.x == 0 ? off_src : off_dst;
    int* cur = blockIdx.x == 0 ? cur_src : cur_dst;
    __shared__ int part[256];
    int t = threadIdx.x;
    int base = t * 40;
    int s = 0;
    for (int i = 0; i < 40; ++i) {
        int idx = base + i;
        if (idx < N_NODES) s += cnt[idx];
    }
    part[t] = s;
    __syncthreads();
    for (int d = 1; d < 256; d <<= 1) {
        int v = (t >= d) ? part[t - d] : 0;
        __syncthreads();
        part[t] += v;
        __syncthreads();
    }
    int run = part[t] - s;
    for (int i = 0; i < 40; ++i) {
        int idx = base + i;
        if (idx < N_NODES) {
            off[idx] = run;
            cur[idx] = run;
            run += cnt[idx];
        }
    }
    if (t == 255) off[N_NODES] = run;
}

// ---------- scatter edges into src-sorted order, build dst-perm, compute h (3 layers, bf16) ----------
__global__ __launch_bounds__(256) void k_scatter_h(const int* __restrict__ ei,
                                                   const float* __restrict__ ea,
                                                   int* __restrict__ cur_src,
                                                   int* __restrict__ cur_dst,
                                                   int* __restrict__ perm,   // src-sorted pos -> dst-sorted pos
                                                   const float* __restrict__ w1a, const float* __restrict__ b1a,
                                                   const float* __restrict__ w1b, const float* __restrict__ b1b,
                                                   const float* __restrict__ w1c, const float* __restrict__ b1c,
                                                   unsigned short* __restrict__ h0,
                                                   unsigned short* __restrict__ h1,
                                                   unsigned short* __restrict__ h2) {
    int e = blockIdx.x * 256 + threadIdx.x;
    if (e >= N_EDGES) return;
    float a0 = ea[2 * e], a1 = ea[2 * e + 1];
    int src = ei[e], dst = ei[N_EDGES + e];
    int pos = atomicAdd(&cur_src[src], 1);
    perm[pos] = atomicAdd(&cur_dst[dst], 1);
    const float* W1[3] = {w1a, w1b, w1c};
    const float* B1[3] = {b1a, b1b, b1c};
    unsigned short* H[3] = {h0, h1, h2};
#pragma unroll
    for (int l = 0; l < 3; ++l) {
        unsigned int pk[16];
#pragma unroll
        for (int j = 0; j < 16; ++j) {
            float v0 = fmaxf(a0 * W1[l][2 * j]     + a1 * W1[l][32 + 2 * j]     + B1[l][2 * j],     0.f);
            float v1 = fmaxf(a0 * W1[l][2 * j + 1] + a1 * W1[l][32 + 2 * j + 1] + B1[l][2 * j + 1], 0.f);
            pk[j] = (unsigned int)f2b(v0) | ((unsigned int)f2b(v1) << 16);
        }
        uint4* dp = (uint4*)(H[l] + (size_t)pos * 32);
        dp[0] = make_uint4(pk[0], pk[1], pk[2], pk[3]);
        dp[1] = make_uint4(pk[4], pk[5], pk[6], pk[7]);
        dp[2] = make_uint4(pk[8], pk[9], pk[10], pk[11]);
        dp[3] = make_uint4(pk[12], pk[13], pk[14], pk[15]);
    }
}

// ---------- G[n, o*32+k] (bf16) = sum_i x[n,i]*w2t[i, o*32+k]; also xb2, agg-init (fp32) ----------
template <int DIN, bool FIRST>
__global__ __launch_bounds__(256) void k_G(const float* __restrict__ xin,
                                           const float* __restrict__ w2t,  // [DIN,1024]
                                           const float* __restrict__ b2,   // [DIN*32]
                                           const float* __restrict__ root, // [DIN,32]
                                           const float* __restrict__ bias, // [32]
                                           unsigned short* __restrict__ Gb,
                                           float* __restrict__ xb2,
                                           float* __restrict__ agg) {
    const int t = threadIdx.x;
    const int n0 = blockIdx.x * 16;

    __shared__ float xs[16 * DIN];
    for (int idx = t; idx < 16 * DIN; idx += 256) {
        int m = idx / DIN, i = idx - m * DIN;
        float v = xin[(size_t)(n0 + m) * DIN + i];
        if (!FIRST) v = v > 0.f ? v : 0.f;
        xs[idx] = v;
    }
    __syncthreads();

    float acc[16][4];
#pragma unroll
    for (int m = 0; m < 16; ++m)
        acc[m][0] = acc[m][1] = acc[m][2] = acc[m][3] = 0.f;

#pragma unroll
    for (int i = 0; i < DIN; ++i) {
        const float4 w = *(const float4*)(w2t + i * 1024 + t * 4);
#pragma unroll
        for (int m = 0; m < 16; ++m) {
            float xv = xs[m * DIN + i];
            acc[m][0] += xv * w.x;
            acc[m][1] += xv * w.y;
            acc[m][2] += xv * w.z;
            acc[m][3] += xv * w.w;
        }
    }
#pragma unroll
    for (int m = 0; m < 16; ++m) {
        unsigned int p0 = (unsigned int)f2b(acc[m][0]) | ((unsigned int)f2b(acc[m][1]) << 16);
        unsigned int p1 = (unsigned int)f2b(acc[m][2]) | ((unsigned int)f2b(acc[m][3]) << 16);
        *(uint2*)(Gb + (size_t)(n0 + m) * 1024 + t * 4) = make_uint2(p0, p1);
    }

    for (int idx = t; idx < 512; idx += 256) {
        int m = idx >> 5, o = idx & 31;
        float ab = 0.f, ar = bias[o];
#pragma unroll
        for (int i = 0; i < DIN; ++i) {
            float xv = xs[m * DIN + i];
            ab += xv * b2[i * 32 + o];
            ar += xv * root[i * 32 + o];
        }
        size_t p = (size_t)(n0 + m) * 32 + o;
        xb2[p] = ab;
        agg[p] = ar;
    }
}

// ---------- MFMA edge kernel: one wave per src node; plain stores to dst-sorted msg rows ----------
__global__ __launch_bounds__(256) void k_edge(const int* __restrict__ off_src,
                                              const int* __restrict__ perm,
                                              const unsigned short* __restrict__ hb,
                                              const unsigned short* __restrict__ Gb,
                                              const float* __restrict__ xb2,
                                              float* __restrict__ msgf) {
    int t = threadIdx.x;
    int lane = t & 63;
    int n = blockIdx.x * 4 + (t >> 6);
    int col = lane & 15;     // C col = o (low half); A row m = edge-in-tile
    int quad = lane >> 4;    // k-block selector

    // B frags: B[k=quad*8+j][o=col] = G_n[o*32 + k]
    const bf16x8 b_lo = *(const bf16x8*)(Gb + (size_t)n * 1024 + col * 32 + quad * 8);
    const bf16x8 b_hi = *(const bf16x8*)(Gb + (size_t)n * 1024 + (col + 16) * 32 + quad * 8);
    float xb_lo = xb2[(size_t)n * 32 + col];
    float xb_hi = xb2[(size_t)n * 32 + 16 + col];

    int jb = off_src[n], je = off_src[n + 1];
    for (int e0 = jb; e0 < je; e0 += 16) {
        int eA = e0 + col;
        bf16x8 afrag = {0, 0, 0, 0, 0, 0, 0, 0};
        if (eA < je) afrag = *(const bf16x8*)(hb + (size_t)eA * 32 + quad * 8);
        f32x4 acc_lo = {xb_lo, xb_lo, xb_lo, xb_lo};
        f32x4 acc_hi = {xb_hi, xb_hi, xb_hi, xb_hi};
        acc_lo = __builtin_amdgcn_mfma_f32_16x16x32_bf16(afrag, b_lo, acc_lo, 0, 0, 0);
        acc_hi = __builtin_amdgcn_mfma_f32_16x16x32_bf16(afrag, b_hi, acc_hi, 0, 0, 0);
#pragma unroll
        for (int r = 0; r < 4; ++r) {
            int er = e0 + quad * 4 + r;       // C row = edge-in-tile (src-sorted pos)
            if (er < je) {
                size_t p = (size_t)perm[er] * 32;
                msgf[p + col] = acc_lo[r];
                msgf[p + 16 + col] = acc_hi[r];
            }
        }
    }
}

// ---------- segment-sum msg rows per dst node (coalesced, no atomics) ----------
__global__ __launch_bounds__(256) void k_agg(const int* __restrict__ off_dst,
                                             const float* __restrict__ msgf,
                                             float* __restrict__ agg) {
    int t = threadIdx.x;
    int n = blockIdx.x * 8 + (t >> 5);       // 8 nodes/block, 32 threads/node
    int o = t & 31;
    int jb = off_dst[n], je = off_dst[n + 1];
    float s = 0.f;
    for (int j = jb; j < je; ++j)
        s += msgf[(size_t)j * 32 + o];
    agg[(size_t)n * 32 + o] += s;            // agg pre-initialized with bias + x@root
}

// ---------- head ----------
__global__ __launch_bounds__(64) void k_final(const float* __restrict__ agg,
                                              const float* __restrict__ fcw,
                                              const float* __restrict__ fcb,
                                              float* __restrict__ out) {
    int n = blockIdx.x * 64 + threadIdx.x;
    if (n >= N_NODES) return;
    float l0 = fcb[0], l1 = fcb[1], l2 = fcb[2], l3 = fcb[3];
#pragma unroll
    for (int o = 0; o < 32; ++o) {
        float xv = agg[(size_t)n * 32 + o];
        xv = xv > 0.f ? xv : 0.f;
        l0 += xv * fcw[o * 4 + 0];
        l1 += xv * fcw[o * 4 + 1];
        l2 += xv * fcw[o * 4 + 2];
        l3 += xv * fcw[o * 4 + 3];
    }
    float m = fmaxf(fmaxf(l0, l1), fmaxf(l2, l3));
    float s = expf(l0 - m) + expf(l1 - m) + expf(l2 - m) + expf(l3 - m);
    float lse = m + logf(s);
    out[(size_t)n * 4 + 0] = l0 - lse;
    out[(size_t)n * 4 + 1] = l1 - lse;
    out[(size_t)n * 4 + 2] = l2 - lse;
    out[(size_t)n * 4 + 3] = l3 - lse;
}

extern "C" void kernel_launch(void* const* d_in, const int* in_sizes, int n_in,
                              void* d_out, int out_size, void* d_ws, size_t ws_size,
                              hipStream_t stream) {
    const float* x0 = (const float*)d_in[0];
    const int*   ei = (const int*)d_in[1];
    const float* ea = (const float*)d_in[2];
    const float *W1[3], *B1[3], *W2[3], *B2[3], *RT[3], *BS[3];
    for (int l = 0; l < 3; ++l) {
        W1[l] = (const float*)d_in[3 + 6 * l];
        B1[l] = (const float*)d_in[4 + 6 * l];
        W2[l] = (const float*)d_in[5 + 6 * l];
        B2[l] = (const float*)d_in[6 + 6 * l];
        RT[l] = (const float*)d_in[7 + 6 * l];
        BS[l] = (const float*)d_in[8 + 6 * l];
    }
    const float* fcw = (const float*)d_in[21];
    const float* fcb = (const float*)d_in[22];
    float* out = (float*)d_out;

    // ---- workspace layout (all segment element counts multiples of 32 -> 128B aligned) ----
    int*   cnt_src = (int*)d_ws;                      // 10240
    int*   cnt_dst = cnt_src + 10240;                 // 10240  (contiguous with cnt_src for k_tw2z zeroing)
    int*   cur_src = cnt_dst + 10240;                 // 10240
    int*   cur_dst = cur_src + 10240;                 // 10240
    int*   off_src = cur_dst + 10240;                 // 10240 (10001 used)
    int*   off_dst = off_src + 10240;                 // 10240 (10001 used)
    int*   perm    = off_dst + 10240;                 // 163840 (160000 used)
    float* w2t0    = (float*)(perm + 163840);         // 4096
    float* w2t1    = w2t0 + 4096;                     // 32768
    float* w2t2    = w2t1 + 32768;                    // 32768
    float* xb2     = w2t2 + 32768;                    // 320000
    float* aggA    = xb2 + 320000;                    // 320000
    float* aggB    = aggA + 320000;                   // 320000
    float* msgf    = aggB + 320000;                   // 5,120,000
    unsigned short* h0 = (unsigned short*)(msgf + 5120000);  // 5,120,000
    unsigned short* h1 = h0 + 5120000;                       // 5,120,000
    unsigned short* h2 = h1 + 5120000;                       // 5,120,000
    unsigned short* Gb = h2 + 5120000;                       // 10,240,000

    const int gE256 = (N_EDGES + 255) / 256;   // 625
    const int gG    = N_NODES / 16;            // 625
    const int gEdge = N_NODES / 4;             // 2500 (1 wave per src node)
    const int gAgg  = N_NODES / 8;             // 1250

    // ---- once-per-call preprocessing ----
    k_tw2z<<<352, 256, 0, stream>>>(W2[0], W2[1], W2[2], w2t0, w2t1, w2t2, cnt_src);
    k_hist<<<gE256, 256, 0, stream>>>(ei, cnt_src, cnt_dst);
    k_scan<<<2, 256, 0, stream>>>(cnt_src, cnt_dst, off_src, off_dst, cur_src, cur_dst);
    k_scatter_h<<<gE256, 256, 0, stream>>>(ei, ea, cur_src, cur_dst, perm,
                                           W1[0], B1[0], W1[1], B1[1], W1[2], B1[2],
                                           h0, h1, h2);

    // ---- layer 0 (din=4) ----
    k_G<4, true><<<gG, 256, 0, stream>>>(x0, w2t0, B2[0], RT[0], BS[0], Gb, xb2, aggA);
    k_edge<<<gEdge, 256, 0, stream>>>(off_src, perm, h0, Gb, xb2, msgf);
    k_agg<<<gAgg, 256, 0, stream>>>(off_dst, msgf, aggA);

    // ---- layer 1 (din=32) ----
    k_G<32, false><<<gG, 256, 0, stream>>>(aggA, w2t1, B2[1], RT[1], BS[1], Gb, xb2, aggB);
    k_edge<<<gEdge, 256, 0, stream>>>(off_src, perm, h1, Gb, xb2, msgf);
    k_agg<<<gAgg, 256, 0, stream>>>(off_dst, msgf, aggB);

    // ---- layer 2 (din=32) ----
    k_G<32, false><<<gG, 256, 0, stream>>>(aggB, w2t2, B2[2], RT[2], BS[2], Gb, xb2, aggA);
    k_edge<<<gEdge, 256, 0, stream>>>(off_src, perm, h2, Gb, xb2, msgf);
    k_agg<<<gAgg, 256, 0, stream>>>(off_dst, msgf, aggA);

    // ---- head ----
    k_final<<<(N_NODES + 63) / 64, 64, 0, stream>>>(aggA, fcw, fcb, out);
}